// Round 4
// baseline (176.635 us; speedup 1.0000x reference)
//
#include <hip/hip_runtime.h>
#include <stdint.h>

#define N_ 256
#define H_ 1024
#define BS_ 128

// ---------------- workspace layout (floats) ----------------
// T   : [3][128][1024] @ 0       tanh outputs (f,g,k)
// sk  : [128][1024]    @ 393216  1 - tk^2
// oacc: [3][128][256]  @ 524288  fo/go/ko accumulators (zeroed by k1)
// vacc: [2][128][1024] @ 622592  vf/vg accumulators    (zeroed by k1)
// jacc: [2][128][256]  @ 884736  Jf/JG accumulators    (zeroed by k2)
#define WS_T    0
#define WS_SK   393216
#define WS_OACC 524288
#define WS_VACC 622592
#define WS_JACC 884736
#define WS_FLOATS 950272   // 3,801,088 bytes

// ---- K1: layer1 + tanh (+sech^2). grid = 3*4*64 = 768, 2 rows/block ----
__global__ __launch_bounds__(256) void k1_layer1(
    const float* __restrict__ x,
    const float* __restrict__ Wf1, const float* __restrict__ bf1,
    const float* __restrict__ Wg1, const float* __restrict__ bg1,
    const float* __restrict__ Wk1, const float* __restrict__ bk1,
    float* __restrict__ T, float* __restrict__ sk,
    float* __restrict__ oacc, float* __restrict__ vacc)
{
    const int bx = blockIdx.x;          // m*256 + ht*64 + rp
    const int m  = bx >> 8;
    const int ht = (bx & 255) >> 6;
    const int rp = bx & 63;
    const int t  = threadIdx.x;
    const int r0 = rp * 2;
    const int h  = ht * 256 + t;

    // zero accumulators consumed by later kernels (stream order = fence)
    const int gtid = bx * 256 + t;                  // 0 .. 196607
    if (gtid < 3 * BS_ * N_) oacc[gtid] = 0.0f;
    for (int idx = gtid; idx < 2 * BS_ * H_; idx += 768 * 256) vacc[idx] = 0.0f;

    const float* W  = (m == 0) ? Wf1 : (m == 1) ? Wg1 : Wk1;
    const float* b1 = (m == 0) ? bf1 : (m == 1) ? bg1 : bk1;

    __shared__ float xs[2][256];
    xs[0][t] = x[r0 * N_ + t];
    xs[1][t] = x[(r0 + 1) * N_ + t];
    __syncthreads();

    float a0 = b1[h], a1 = a0;
    const float4* w4 = (const float4*)(W + h * N_);
    #pragma unroll 8
    for (int c = 0; c < 64; ++c) {
        float4 w  = w4[c];
        float4 xa = ((const float4*)xs[0])[c];
        float4 xb = ((const float4*)xs[1])[c];
        a0 += w.x * xa.x + w.y * xa.y + w.z * xa.z + w.w * xa.w;
        a1 += w.x * xb.x + w.y * xb.y + w.z * xb.z + w.w * xb.w;
    }
    const float v0 = tanhf(a0), v1 = tanhf(a1);
    T[(m * BS_ + r0) * H_ + h]     = v0;
    T[(m * BS_ + r0 + 1) * H_ + h] = v1;
    if (m == 2) {
        sk[r0 * H_ + h]       = 1.0f - v0 * v0;
        sk[(r0 + 1) * H_ + h] = 1.0f - v1 * v1;
    }
}

// ---- K2: layer2, k-split 4. grid = 3*64*4 = 768, 2 rows/block ----
__global__ __launch_bounds__(256) void k2_layer2(
    const float* __restrict__ T,
    const float* __restrict__ Wf2, const float* __restrict__ bf2,
    const float* __restrict__ Wg2, const float* __restrict__ bg2,
    const float* __restrict__ Wk2, const float* __restrict__ bk2,
    float* __restrict__ oacc, float* __restrict__ jacc)
{
    const int bx = blockIdx.x;          // m*256 + rp*4 + ks
    const int m  = bx >> 8;
    const int rp = (bx & 255) >> 2;
    const int ks = bx & 3;
    const int t  = threadIdx.x;         // output channel i
    const int r0 = rp * 2;
    const int h0 = ks * 256;

    const int gtid = bx * 256 + t;
    if (gtid < 2 * BS_ * N_) jacc[gtid] = 0.0f;   // consumed by k4

    const float* W  = (m == 0) ? Wf2 : (m == 1) ? Wg2 : Wk2;
    const float* b2 = (m == 0) ? bf2 : (m == 1) ? bg2 : bk2;

    __shared__ float ts[2][256];
    ts[0][t] = T[(m * BS_ + r0) * H_ + h0 + t];
    ts[1][t] = T[(m * BS_ + r0 + 1) * H_ + h0 + t];
    __syncthreads();

    const float bv = (ks == 0) ? b2[t] : 0.0f;
    float a0 = bv, a1 = bv;
    const float4* w4 = (const float4*)(W + t * H_ + h0);
    #pragma unroll 8
    for (int c = 0; c < 64; ++c) {
        float4 w  = w4[c];
        float4 ta = ((const float4*)ts[0])[c];
        float4 tb = ((const float4*)ts[1])[c];
        a0 += w.x * ta.x + w.y * ta.y + w.z * ta.z + w.w * ta.w;
        a1 += w.x * tb.x + w.y * tb.y + w.z * tb.z + w.w * tb.w;
    }
    atomicAdd(&oacc[(m * BS_ + r0) * N_ + t], a0);
    atomicAdd(&oacc[(m * BS_ + r0 + 1) * N_ + t], a1);
}

// ---- K3: vf/vg partial = fo/go @ Wk2, i-split 8. grid = 128*8 = 1024 ----
// thread t owns cols 4t..4t+3 (float4 coalesced), 8 indep FMA chains
__global__ __launch_bounds__(256) void k3_v(
    const float* __restrict__ Wk2,
    const float* __restrict__ oacc,
    float* __restrict__ vacc)
{
    const int r   = blockIdx.x >> 3;
    const int isl = blockIdx.x & 7;
    const int t   = threadIdx.x;
    const int i0  = isl * 32;

    __shared__ float fos[32], gos[32];
    if (t < 32)       fos[t]      = oacc[r * N_ + i0 + t];
    else if (t < 64)  gos[t - 32] = oacc[(BS_ + r) * N_ + i0 + (t - 32)];
    __syncthreads();

    float4 af = {0.f, 0.f, 0.f, 0.f};
    float4 ag = {0.f, 0.f, 0.f, 0.f};
    #pragma unroll 8
    for (int ii = 0; ii < 32; ++ii) {
        float4 w = ((const float4*)(Wk2 + (i0 + ii) * H_))[t];
        const float fv = fos[ii], gv = gos[ii];
        af.x += w.x * fv; af.y += w.y * fv; af.z += w.z * fv; af.w += w.w * fv;
        ag.x += w.x * gv; ag.y += w.y * gv; ag.z += w.z * gv; ag.w += w.w * gv;
    }
    float* vf = vacc + r * H_ + 4 * t;
    atomicAdd(vf + 0, af.x); atomicAdd(vf + 1, af.y);
    atomicAdd(vf + 2, af.z); atomicAdd(vf + 3, af.w);
    float* vg = vacc + (BS_ + r) * H_ + 4 * t;
    atomicAdd(vg + 0, ag.x); atomicAdd(vg + 1, ag.y);
    atomicAdd(vg + 2, ag.z); atomicAdd(vg + 3, ag.w);
}

// ---- K4: Jf/JG = (sk .* v) @ Wk1, h-split 8. grid = 128*8 = 1024 ----
__global__ __launch_bounds__(256) void k4_j(
    const float* __restrict__ Wk1,
    const float* __restrict__ vacc, const float* __restrict__ sk,
    float* __restrict__ jacc)
{
    const int r  = blockIdx.x >> 3;
    const int ks = blockIdx.x & 7;
    const int t  = threadIdx.x;         // output j
    const int h0 = ks * 128;

    __shared__ float sf[128], sg[128];
    if (t < 128) sf[t] = sk[r * H_ + h0 + t] * vacc[r * H_ + h0 + t];
    else {
        const int u = t - 128;
        sg[u] = sk[r * H_ + h0 + u] * vacc[(BS_ + r) * H_ + h0 + u];
    }
    __syncthreads();

    float aJf = 0.f, aJg = 0.f;
    const float* w = Wk1 + h0 * N_ + t;
    #pragma unroll 8
    for (int hh = 0; hh < 128; ++hh) {
        const float wv = w[hh * N_];
        aJf += sf[hh] * wv;
        aJg += sg[hh] * wv;
    }
    atomicAdd(&jacc[r * N_ + t], aJf);
    atomicAdd(&jacc[(BS_ + r) * N_ + t], aJg);
}

// ---- K5: per-row reductions + mask + output. grid = 128 ----
__global__ __launch_bounds__(256) void k5_final(
    const float* __restrict__ oacc,
    const float* __restrict__ jacc,
    float* __restrict__ out)
{
    const int r = blockIdx.x;
    const int t = threadIdx.x;
    __shared__ float red[12];

    const float fo = oacc[r * N_ + t];
    const float go = oacc[(BS_ + r) * N_ + t];
    const float ko = oacc[(2 * BS_ + r) * N_ + t];
    const float jf = jacc[r * N_ + t];
    const float jg = jacc[(BS_ + r) * N_ + t];

    float v0 = ko * ko;
    float v1 = jf * jf;
    float v2 = ko * jg;
    #pragma unroll
    for (int o = 32; o > 0; o >>= 1) {
        v0 += __shfl_xor(v0, o, 64);
        v1 += __shfl_xor(v1, o, 64);
        v2 += __shfl_xor(v2, o, 64);
    }
    const int wid = t >> 6;
    if ((t & 63) == 0) {
        red[wid * 3 + 0] = v0;
        red[wid * 3 + 1] = v1;
        red[wid * 3 + 2] = v2;
    }
    __syncthreads();
    const float kn2 = red[0] + red[3] + red[6] + red[9];
    const float jf2 = red[1] + red[4] + red[7] + red[10];
    const float kjg = red[2] + red[5] + red[8] + red[11];

    const float knorm = sqrtf(kn2);
    const float kn4 = kn2 * kn2;
    const float kn8 = kn4 * kn4;
    const float c1 = sqrtf(jf2) - 60.0f * kn8 * knorm;
    const float c2 = kjg - 20.0f * kn8 * kn2;
    const float scale = ((c1 > 1e-8f) || (c2 < -1e-8f)) ? 0.5f : 1.0f;

    out[r * N_ + t] = (fo + go) * scale;
}

// ================= fallback: round-2 proven fused kernel =================
__global__ __launch_bounds__(256) void manifold_fused(
    const float* __restrict__ x,
    const float* __restrict__ Wf1, const float* __restrict__ bf1v,
    const float* __restrict__ Wf2, const float* __restrict__ bf2v,
    const float* __restrict__ Wg1, const float* __restrict__ bg1v,
    const float* __restrict__ Wg2, const float* __restrict__ bg2v,
    const float* __restrict__ Wk1, const float* __restrict__ bk1v,
    const float* __restrict__ Wk2, const float* __restrict__ bk2v,
    float* __restrict__ out)
{
    const int b = blockIdx.x;
    const int t = threadIdx.x;
    __shared__ float xs[N_];
    __shared__ float tf[H_], tg[H_], tk[H_], sk[H_];
    __shared__ float fo[N_], go[N_];
    __shared__ float sfv[H_], sgv[H_];
    __shared__ float red[12];

    xs[t] = x[b * N_ + t];
    __syncthreads();
    {
        float acc[12];
        const float4* rows[12];
        #pragma unroll
        for (int m = 0; m < 4; ++m) {
            const int h = t + m * 256;
            rows[m]     = (const float4*)(Wf1 + h * N_);
            rows[4 + m] = (const float4*)(Wg1 + h * N_);
            rows[8 + m] = (const float4*)(Wk1 + h * N_);
            acc[m] = bf1v[h]; acc[4 + m] = bg1v[h]; acc[8 + m] = bk1v[h];
        }
        const float4* xs4 = (const float4*)xs;
        #pragma unroll 2
        for (int c = 0; c < 64; ++c) {
            float4 a = xs4[c];
            #pragma unroll
            for (int r = 0; r < 12; ++r) {
                float4 w = rows[r][c];
                acc[r] += w.x * a.x + w.y * a.y + w.z * a.z + w.w * a.w;
            }
        }
        #pragma unroll
        for (int m = 0; m < 4; ++m) {
            const int h = t + m * 256;
            float vtf = tanhf(acc[m]);
            float vtg = tanhf(acc[4 + m]);
            float vtk = tanhf(acc[8 + m]);
            tf[h] = vtf; tg[h] = vtg; tk[h] = vtk; sk[h] = 1.0f - vtk * vtk;
        }
    }
    __syncthreads();
    float af = bf2v[t], ag = bg2v[t], ak = bk2v[t];
    {
        const float4* rf = (const float4*)(Wf2 + t * H_);
        const float4* rg = (const float4*)(Wg2 + t * H_);
        const float4* rk = (const float4*)(Wk2 + t * H_);
        #pragma unroll 2
        for (int c = 0; c < 256; ++c) {
            float4 wf = rf[c], wg = rg[c], wk = rk[c];
            float4 vf = ((const float4*)tf)[c];
            af += wf.x*vf.x + wf.y*vf.y + wf.z*vf.z + wf.w*vf.w;
            float4 vg = ((const float4*)tg)[c];
            ag += wg.x*vg.x + wg.y*vg.y + wg.z*vg.z + wg.w*vg.w;
            float4 vk = ((const float4*)tk)[c];
            ak += wk.x*vk.x + wk.y*vk.y + wk.z*vk.z + wk.w*vk.w;
        }
    }
    fo[t] = af; go[t] = ag;
    __syncthreads();
    {
        float vf[4] = {0.f,0.f,0.f,0.f}, vg[4] = {0.f,0.f,0.f,0.f};
        const float* base = Wk2 + 4 * t;
        #pragma unroll 4
        for (int i = 0; i < N_; ++i) {
            float4 w = *(const float4*)(base + i * H_);
            float fv = fo[i], gv = go[i];
            vf[0]+=w.x*fv; vf[1]+=w.y*fv; vf[2]+=w.z*fv; vf[3]+=w.w*fv;
            vg[0]+=w.x*gv; vg[1]+=w.y*gv; vg[2]+=w.z*gv; vg[3]+=w.w*gv;
        }
        #pragma unroll
        for (int c = 0; c < 4; ++c) {
            sfv[4*t+c] = sk[4*t+c]*vf[c];
            sgv[4*t+c] = sk[4*t+c]*vg[c];
        }
    }
    __syncthreads();
    float jf = 0.f, jg = 0.f;
    {
        const float* col = Wk1 + t;
        #pragma unroll 4
        for (int c = 0; c < 256; ++c) {
            float4 s4 = ((const float4*)sfv)[c];
            float4 g4 = ((const float4*)sgv)[c];
            const int h = c * 4;
            float w0 = col[(h+0)*N_], w1 = col[(h+1)*N_];
            float w2 = col[(h+2)*N_], w3 = col[(h+3)*N_];
            jf += s4.x*w0 + s4.y*w1 + s4.z*w2 + s4.w*w3;
            jg += g4.x*w0 + g4.y*w1 + g4.z*w2 + g4.w*w3;
        }
    }
    float v0 = ak*ak, v1 = jf*jf, v2 = ak*jg;
    #pragma unroll
    for (int o = 32; o > 0; o >>= 1) {
        v0 += __shfl_xor(v0, o, 64);
        v1 += __shfl_xor(v1, o, 64);
        v2 += __shfl_xor(v2, o, 64);
    }
    const int wid = t >> 6;
    if ((t & 63) == 0) {
        red[wid*3+0] = v0; red[wid*3+1] = v1; red[wid*3+2] = v2;
    }
    __syncthreads();
    const float kn2 = red[0]+red[3]+red[6]+red[9];
    const float jf2 = red[1]+red[4]+red[7]+red[10];
    const float kjg = red[2]+red[5]+red[8]+red[11];
    const float knorm = sqrtf(kn2);
    const float kn4 = kn2*kn2, kn8 = kn4*kn4;
    const float c1 = sqrtf(jf2) - 60.0f*kn8*knorm;
    const float c2 = kjg - 20.0f*kn8*kn2;
    const float scale = ((c1 > 1e-8f) || (c2 < -1e-8f)) ? 0.5f : 1.0f;
    out[b*N_+t] = (af+ag)*scale;
}

extern "C" void kernel_launch(void* const* d_in, const int* in_sizes, int n_in,
                              void* d_out, int out_size, void* d_ws, size_t ws_size,
                              hipStream_t stream) {
    const float* x    = (const float*)d_in[1];
    const float* Wf1  = (const float*)d_in[2];
    const float* bf1v = (const float*)d_in[3];
    const float* Wf2  = (const float*)d_in[4];
    const float* bf2v = (const float*)d_in[5];
    const float* Wg1  = (const float*)d_in[6];
    const float* bg1v = (const float*)d_in[7];
    const float* Wg2  = (const float*)d_in[8];
    const float* bg2v = (const float*)d_in[9];
    const float* Wk1  = (const float*)d_in[10];
    const float* bk1v = (const float*)d_in[11];
    const float* Wk2  = (const float*)d_in[12];
    const float* bk2v = (const float*)d_in[13];
    float* out = (float*)d_out;

    if (ws_size < (size_t)WS_FLOATS * sizeof(float)) {
        manifold_fused<<<BS_, 256, 0, stream>>>(
            x, Wf1, bf1v, Wf2, bf2v, Wg1, bg1v, Wg2, bg2v,
            Wk1, bk1v, Wk2, bk2v, out);
        return;
    }

    float* ws   = (float*)d_ws;
    float* T    = ws + WS_T;
    float* sk   = ws + WS_SK;
    float* oacc = ws + WS_OACC;
    float* vacc = ws + WS_VACC;
    float* jacc = ws + WS_JACC;

    k1_layer1<<<768, 256, 0, stream>>>(x, Wf1, bf1v, Wg1, bg1v, Wk1, bk1v,
                                       T, sk, oacc, vacc);
    k2_layer2<<<768, 256, 0, stream>>>(T, Wf2, bf2v, Wg2, bg2v, Wk2, bk2v,
                                       oacc, jacc);
    k3_v     <<<1024, 256, 0, stream>>>(Wk2, oacc, vacc);
    k4_j     <<<1024, 256, 0, stream>>>(Wk1, vacc, sk, jacc);
    k5_final <<<BS_, 256, 0, stream>>>(oacc, jacc, out);
}

// Round 5
// 154.161 us; speedup vs baseline: 1.1458x; 1.1458x over previous
//
#include <hip/hip_runtime.h>
#include <stdint.h>

#define N_ 256
#define H_ 1024
#define BS_ 128

// ---------------- workspace layout (floats) ----------------
// T   : [3][128][1024] @ 0       tanh outputs (f,g,k)
// sk  : [128][1024]    @ 393216  1 - tk^2
// oacc: [3][128][256]  @ 524288  fo/go/ko accumulators (zeroed by k1)
// jacc: [2][128][256]  @ 622592  Jf/JG accumulators    (zeroed by k1)
#define WS_T    0
#define WS_SK   393216
#define WS_OACC 524288
#define WS_JACC 622592
#define WS_FLOATS 688128   // 2,752,512 bytes

// ---- K1: layer1 + tanh (+sech^2). grid = 3*4*64 = 768, 2 rows/block ----
__global__ __launch_bounds__(256) void k1_layer1(
    const float* __restrict__ x,
    const float* __restrict__ Wf1, const float* __restrict__ bf1,
    const float* __restrict__ Wg1, const float* __restrict__ bg1,
    const float* __restrict__ Wk1, const float* __restrict__ bk1,
    float* __restrict__ T, float* __restrict__ sk,
    float* __restrict__ oacc, float* __restrict__ jacc)
{
    const int bx = blockIdx.x;          // m*256 + ht*64 + rp
    const int m  = bx >> 8;
    const int ht = (bx & 255) >> 6;
    const int rp = bx & 63;
    const int t  = threadIdx.x;
    const int r0 = rp * 2;
    const int h  = ht * 256 + t;

    // zero accumulators consumed by later kernels (stream order = fence)
    const int gtid = bx * 256 + t;                  // 0 .. 196607
    if (gtid < 3 * BS_ * N_) oacc[gtid] = 0.0f;                       // 98304
    else if (gtid < 5 * BS_ * N_) jacc[gtid - 3 * BS_ * N_] = 0.0f;   // 65536

    const float* W  = (m == 0) ? Wf1 : (m == 1) ? Wg1 : Wk1;
    const float* b1 = (m == 0) ? bf1 : (m == 1) ? bg1 : bk1;

    __shared__ float xs[2][256];
    xs[0][t] = x[r0 * N_ + t];
    xs[1][t] = x[(r0 + 1) * N_ + t];
    __syncthreads();

    float a0 = b1[h], a1 = a0;
    const float4* w4 = (const float4*)(W + h * N_);
    #pragma unroll 8
    for (int c = 0; c < 64; ++c) {
        float4 w  = w4[c];
        float4 xa = ((const float4*)xs[0])[c];
        float4 xb = ((const float4*)xs[1])[c];
        a0 += w.x * xa.x + w.y * xa.y + w.z * xa.z + w.w * xa.w;
        a1 += w.x * xb.x + w.y * xb.y + w.z * xb.z + w.w * xb.w;
    }
    const float v0 = tanhf(a0), v1 = tanhf(a1);
    T[(m * BS_ + r0) * H_ + h]     = v0;
    T[(m * BS_ + r0 + 1) * H_ + h] = v1;
    if (m == 2) {
        sk[r0 * H_ + h]       = 1.0f - v0 * v0;
        sk[(r0 + 1) * H_ + h] = 1.0f - v1 * v1;
    }
}

// ---- K2: layer2, k-split 4. grid = 3*64*4 = 768, 2 rows/block ----
__global__ __launch_bounds__(256) void k2_layer2(
    const float* __restrict__ T,
    const float* __restrict__ Wf2, const float* __restrict__ bf2,
    const float* __restrict__ Wg2, const float* __restrict__ bg2,
    const float* __restrict__ Wk2, const float* __restrict__ bk2,
    float* __restrict__ oacc)
{
    const int bx = blockIdx.x;          // m*256 + rp*4 + ks
    const int m  = bx >> 8;
    const int rp = (bx & 255) >> 2;
    const int ks = bx & 3;
    const int t  = threadIdx.x;         // output channel i
    const int r0 = rp * 2;
    const int h0 = ks * 256;

    const float* W  = (m == 0) ? Wf2 : (m == 1) ? Wg2 : Wk2;
    const float* b2 = (m == 0) ? bf2 : (m == 1) ? bg2 : bk2;

    __shared__ float ts[2][256];
    ts[0][t] = T[(m * BS_ + r0) * H_ + h0 + t];
    ts[1][t] = T[(m * BS_ + r0 + 1) * H_ + h0 + t];
    __syncthreads();

    const float bv = (ks == 0) ? b2[t] : 0.0f;
    float a0 = bv, a1 = bv;
    const float4* w4 = (const float4*)(W + t * H_ + h0);
    #pragma unroll 8
    for (int c = 0; c < 64; ++c) {
        float4 w  = w4[c];
        float4 ta = ((const float4*)ts[0])[c];
        float4 tb = ((const float4*)ts[1])[c];
        a0 += w.x * ta.x + w.y * ta.y + w.z * ta.z + w.w * ta.w;
        a1 += w.x * tb.x + w.y * tb.y + w.z * tb.z + w.w * tb.w;
    }
    atomicAdd(&oacc[(m * BS_ + r0) * N_ + t], a0);
    atomicAdd(&oacc[(m * BS_ + r0 + 1) * N_ + t], a1);
}

// ---- K34: fused v + J. grid = 128*4 = 512, block = (row, h-quarter) ----
// Phase A: v[h] = sum_i {fo,go}[i] * Wk2[i][h], scaled by sech^2 -> LDS
// Phase B: J[j] += sum_h sfv[h] * Wk1[h][j], 4-way jacc atomics
__global__ __launch_bounds__(256) void k34_vj(
    const float* __restrict__ Wk1, const float* __restrict__ Wk2,
    const float* __restrict__ oacc, const float* __restrict__ sk,
    float* __restrict__ jacc)
{
    const int r  = blockIdx.x >> 2;
    const int q  = blockIdx.x & 3;
    const int t  = threadIdx.x;
    const int h0 = q * 256;
    const int h  = h0 + t;

    __shared__ float fos[256], gos[256];
    __shared__ float sfv[256], sgv[256];
    fos[t] = oacc[r * N_ + t];
    gos[t] = oacc[(BS_ + r) * N_ + t];
    __syncthreads();

    float vf = 0.f, vg = 0.f;
    const float* w2 = Wk2 + h;              // Wk2[i][h], coalesced over t
    #pragma unroll 8
    for (int i = 0; i < 256; ++i) {
        const float wv = w2[i * H_];
        vf += wv * fos[i];                  // broadcast LDS read: conflict-free
        vg += wv * gos[i];
    }
    const float s = sk[r * H_ + h];
    sfv[t] = s * vf;
    sgv[t] = s * vg;
    __syncthreads();

    float aJf = 0.f, aJg = 0.f;
    const float* w1 = Wk1 + h0 * N_ + t;    // Wk1[h0+hh][j=t], coalesced over t
    #pragma unroll 8
    for (int hh = 0; hh < 256; ++hh) {
        const float wv = w1[hh * N_];
        aJf += sfv[hh] * wv;
        aJg += sgv[hh] * wv;
    }
    atomicAdd(&jacc[r * N_ + t], aJf);
    atomicAdd(&jacc[(BS_ + r) * N_ + t], aJg);
}

// ---- K5: per-row reductions + mask + output. grid = 128 ----
__global__ __launch_bounds__(256) void k5_final(
    const float* __restrict__ oacc,
    const float* __restrict__ jacc,
    float* __restrict__ out)
{
    const int r = blockIdx.x;
    const int t = threadIdx.x;
    __shared__ float red[12];

    const float fo = oacc[r * N_ + t];
    const float go = oacc[(BS_ + r) * N_ + t];
    const float ko = oacc[(2 * BS_ + r) * N_ + t];
    const float jf = jacc[r * N_ + t];
    const float jg = jacc[(BS_ + r) * N_ + t];

    float v0 = ko * ko;
    float v1 = jf * jf;
    float v2 = ko * jg;
    #pragma unroll
    for (int o = 32; o > 0; o >>= 1) {
        v0 += __shfl_xor(v0, o, 64);
        v1 += __shfl_xor(v1, o, 64);
        v2 += __shfl_xor(v2, o, 64);
    }
    const int wid = t >> 6;
    if ((t & 63) == 0) {
        red[wid * 3 + 0] = v0;
        red[wid * 3 + 1] = v1;
        red[wid * 3 + 2] = v2;
    }
    __syncthreads();
    const float kn2 = red[0] + red[3] + red[6] + red[9];
    const float jf2 = red[1] + red[4] + red[7] + red[10];
    const float kjg = red[2] + red[5] + red[8] + red[11];

    const float knorm = sqrtf(kn2);
    const float kn4 = kn2 * kn2;
    const float kn8 = kn4 * kn4;
    const float c1 = sqrtf(jf2) - 60.0f * kn8 * knorm;
    const float c2 = kjg - 20.0f * kn8 * kn2;
    const float scale = ((c1 > 1e-8f) || (c2 < -1e-8f)) ? 0.5f : 1.0f;

    out[r * N_ + t] = (fo + go) * scale;
}

// ================= fallback: round-2 proven fused kernel =================
__global__ __launch_bounds__(256) void manifold_fused(
    const float* __restrict__ x,
    const float* __restrict__ Wf1, const float* __restrict__ bf1v,
    const float* __restrict__ Wf2, const float* __restrict__ bf2v,
    const float* __restrict__ Wg1, const float* __restrict__ bg1v,
    const float* __restrict__ Wg2, const float* __restrict__ bg2v,
    const float* __restrict__ Wk1, const float* __restrict__ bk1v,
    const float* __restrict__ Wk2, const float* __restrict__ bk2v,
    float* __restrict__ out)
{
    const int b = blockIdx.x;
    const int t = threadIdx.x;
    __shared__ float xs[N_];
    __shared__ float tf[H_], tg[H_], tk[H_], sk[H_];
    __shared__ float fo[N_], go[N_];
    __shared__ float sfv[H_], sgv[H_];
    __shared__ float red[12];

    xs[t] = x[b * N_ + t];
    __syncthreads();
    {
        float acc[12];
        const float4* rows[12];
        #pragma unroll
        for (int m = 0; m < 4; ++m) {
            const int h = t + m * 256;
            rows[m]     = (const float4*)(Wf1 + h * N_);
            rows[4 + m] = (const float4*)(Wg1 + h * N_);
            rows[8 + m] = (const float4*)(Wk1 + h * N_);
            acc[m] = bf1v[h]; acc[4 + m] = bg1v[h]; acc[8 + m] = bk1v[h];
        }
        const float4* xs4 = (const float4*)xs;
        #pragma unroll 2
        for (int c = 0; c < 64; ++c) {
            float4 a = xs4[c];
            #pragma unroll
            for (int r = 0; r < 12; ++r) {
                float4 w = rows[r][c];
                acc[r] += w.x * a.x + w.y * a.y + w.z * a.z + w.w * a.w;
            }
        }
        #pragma unroll
        for (int m = 0; m < 4; ++m) {
            const int h = t + m * 256;
            float vtf = tanhf(acc[m]);
            float vtg = tanhf(acc[4 + m]);
            float vtk = tanhf(acc[8 + m]);
            tf[h] = vtf; tg[h] = vtg; tk[h] = vtk; sk[h] = 1.0f - vtk * vtk;
        }
    }
    __syncthreads();
    float af = bf2v[t], ag = bg2v[t], ak = bk2v[t];
    {
        const float4* rf = (const float4*)(Wf2 + t * H_);
        const float4* rg = (const float4*)(Wg2 + t * H_);
        const float4* rk = (const float4*)(Wk2 + t * H_);
        #pragma unroll 2
        for (int c = 0; c < 256; ++c) {
            float4 wf = rf[c], wg = rg[c], wk = rk[c];
            float4 vf = ((const float4*)tf)[c];
            af += wf.x*vf.x + wf.y*vf.y + wf.z*vf.z + wf.w*vf.w;
            float4 vg = ((const float4*)tg)[c];
            ag += wg.x*vg.x + wg.y*vg.y + wg.z*vg.z + wg.w*vg.w;
            float4 vk = ((const float4*)tk)[c];
            ak += wk.x*vk.x + wk.y*vk.y + wk.z*vk.z + wk.w*vk.w;
        }
    }
    fo[t] = af; go[t] = ag;
    __syncthreads();
    {
        float vf[4] = {0.f,0.f,0.f,0.f}, vg[4] = {0.f,0.f,0.f,0.f};
        const float* base = Wk2 + 4 * t;
        #pragma unroll 4
        for (int i = 0; i < N_; ++i) {
            float4 w = *(const float4*)(base + i * H_);
            float fv = fo[i], gv = go[i];
            vf[0]+=w.x*fv; vf[1]+=w.y*fv; vf[2]+=w.z*fv; vf[3]+=w.w*fv;
            vg[0]+=w.x*gv; vg[1]+=w.y*gv; vg[2]+=w.z*gv; vg[3]+=w.w*gv;
        }
        #pragma unroll
        for (int c = 0; c < 4; ++c) {
            sfv[4*t+c] = sk[4*t+c]*vf[c];
            sgv[4*t+c] = sk[4*t+c]*vg[c];
        }
    }
    __syncthreads();
    float jf = 0.f, jg = 0.f;
    {
        const float* col = Wk1 + t;
        #pragma unroll 4
        for (int c = 0; c < 256; ++c) {
            float4 s4 = ((const float4*)sfv)[c];
            float4 g4 = ((const float4*)sgv)[c];
            const int h = c * 4;
            float w0 = col[(h+0)*N_], w1 = col[(h+1)*N_];
            float w2 = col[(h+2)*N_], w3 = col[(h+3)*N_];
            jf += s4.x*w0 + s4.y*w1 + s4.z*w2 + s4.w*w3;
            jg += g4.x*w0 + g4.y*w1 + g4.z*w2 + g4.w*w3;
        }
    }
    float v0 = ak*ak, v1 = jf*jf, v2 = ak*jg;
    #pragma unroll
    for (int o = 32; o > 0; o >>= 1) {
        v0 += __shfl_xor(v0, o, 64);
        v1 += __shfl_xor(v1, o, 64);
        v2 += __shfl_xor(v2, o, 64);
    }
    const int wid = t >> 6;
    if ((t & 63) == 0) {
        red[wid*3+0] = v0; red[wid*3+1] = v1; red[wid*3+2] = v2;
    }
    __syncthreads();
    const float kn2 = red[0]+red[3]+red[6]+red[9];
    const float jf2 = red[1]+red[4]+red[7]+red[10];
    const float kjg = red[2]+red[5]+red[8]+red[11];
    const float knorm = sqrtf(kn2);
    const float kn4 = kn2*kn2, kn8 = kn4*kn4;
    const float c1 = sqrtf(jf2) - 60.0f*kn8*knorm;
    const float c2 = kjg - 20.0f*kn8*kn2;
    const float scale = ((c1 > 1e-8f) || (c2 < -1e-8f)) ? 0.5f : 1.0f;
    out[b*N_+t] = (af+ag)*scale;
}

extern "C" void kernel_launch(void* const* d_in, const int* in_sizes, int n_in,
                              void* d_out, int out_size, void* d_ws, size_t ws_size,
                              hipStream_t stream) {
    const float* x    = (const float*)d_in[1];
    const float* Wf1  = (const float*)d_in[2];
    const float* bf1v = (const float*)d_in[3];
    const float* Wf2  = (const float*)d_in[4];
    const float* bf2v = (const float*)d_in[5];
    const float* Wg1  = (const float*)d_in[6];
    const float* bg1v = (const float*)d_in[7];
    const float* Wg2  = (const float*)d_in[8];
    const float* bg2v = (const float*)d_in[9];
    const float* Wk1  = (const float*)d_in[10];
    const float* bk1v = (const float*)d_in[11];
    const float* Wk2  = (const float*)d_in[12];
    const float* bk2v = (const float*)d_in[13];
    float* out = (float*)d_out;

    if (ws_size < (size_t)WS_FLOATS * sizeof(float)) {
        manifold_fused<<<BS_, 256, 0, stream>>>(
            x, Wf1, bf1v, Wf2, bf2v, Wg1, bg1v, Wg2, bg2v,
            Wk1, bk1v, Wk2, bk2v, out);
        return;
    }

    float* ws   = (float*)d_ws;
    float* T    = ws + WS_T;
    float* sk   = ws + WS_SK;
    float* oacc = ws + WS_OACC;
    float* jacc = ws + WS_JACC;

    k1_layer1<<<768, 256, 0, stream>>>(x, Wf1, bf1v, Wg1, bg1v, Wk1, bk1v,
                                       T, sk, oacc, jacc);
    k2_layer2<<<768, 256, 0, stream>>>(T, Wf2, bf2v, Wg2, bg2v, Wk2, bk2v,
                                       oacc);
    k34_vj   <<<512, 256, 0, stream>>>(Wk1, Wk2, oacc, sk, jacc);
    k5_final <<<BS_, 256, 0, stream>>>(oacc, jacc, out);
}